// Round 3
// baseline (489.661 us; speedup 1.0000x reference)
//
#include <hip/hip_runtime.h>

#define N_NODES_C 100000
#define N_EDGES_C 800000
#define FEATS 100
#define NCLS 50
#define GENE 20000
#define SCAN_BLK 1024
#define SCAN_NBLK ((N_NODES_C + SCAN_BLK - 1) / SCAN_BLK)   // 98
#define ROWS_PER_BLK 32
#define NROUNDS (N_NODES_C / ROWS_PER_BLK)                   // 3125 exact

// ---------------------------------------------------------------------------
// Degree count (int atomics)
// ---------------------------------------------------------------------------
__global__ void deg_count_kernel(const int* __restrict__ dst,
                                 int* __restrict__ deg) {
    int e = blockIdx.x * blockDim.x + threadIdx.x;
    if (e >= N_EDGES_C) return;
    atomicAdd(&deg[dst[e]], 1);
}

// ---------------------------------------------------------------------------
// 3-kernel exclusive scan over deg[100000] -> row_ptr[100001]
// ---------------------------------------------------------------------------
__global__ __launch_bounds__(1024) void scan1_kernel(int* __restrict__ deg,
                                                     int* __restrict__ bsum) {
    __shared__ int wsum[16];
    const int i = blockIdx.x * SCAN_BLK + threadIdx.x;
    const int lane = threadIdx.x & 63;
    const int wid = threadIdx.x >> 6;
    int v = (i < N_NODES_C) ? deg[i] : 0;
    #pragma unroll
    for (int d = 1; d < 64; d <<= 1) {
        int t = __shfl_up(v, d);
        if (lane >= d) v += t;
    }
    if (lane == 63) wsum[wid] = v;
    __syncthreads();
    if (wid == 0) {
        int s = (lane < 16) ? wsum[lane] : 0;
        #pragma unroll
        for (int d = 1; d < 16; d <<= 1) {
            int t = __shfl_up(s, d);
            if (lane >= d) s += t;
        }
        if (lane < 16) wsum[lane] = s;
    }
    __syncthreads();
    if (wid > 0) v += wsum[wid - 1];
    if (i < N_NODES_C) deg[i] = v;
    if (threadIdx.x == SCAN_BLK - 1) bsum[blockIdx.x] = v;
}

__global__ void scan2_kernel(int* __restrict__ bsum) {
    __shared__ int tmp[SCAN_NBLK];
    if (threadIdx.x < SCAN_NBLK) tmp[threadIdx.x] = bsum[threadIdx.x];
    __syncthreads();
    if (threadIdx.x == 0) {
        int off = 0;
        for (int j = 0; j < SCAN_NBLK; ++j) { int t = tmp[j]; tmp[j] = off; off += t; }
    }
    __syncthreads();
    if (threadIdx.x < SCAN_NBLK) bsum[threadIdx.x] = tmp[threadIdx.x];
}

__global__ __launch_bounds__(1024) void scan3_kernel(const int* __restrict__ incl,
                                                     const int* __restrict__ boff,
                                                     int* __restrict__ rp,
                                                     int* __restrict__ cursor) {
    int i = blockIdx.x * SCAN_BLK + threadIdx.x;
    if (i >= N_NODES_C) return;
    int v = incl[i] + boff[blockIdx.x];
    rp[i + 1] = v;
    cursor[i + 1] = v;
    if (i == 0) { rp[0] = 0; cursor[0] = 0; }
}

// ---------------------------------------------------------------------------
// CSR fill: per edge compute scale inline, append (src, scale) to dst bucket
// ---------------------------------------------------------------------------
__global__ void csr_fill_kernel(const int* __restrict__ node_ids,
                                const int* __restrict__ src,
                                const int* __restrict__ dst,
                                const float* __restrict__ ew,
                                const float* __restrict__ alpha,
                                int* __restrict__ cursor,
                                int2* __restrict__ csr) {
    int e = blockIdx.x * blockDim.x + threadIdx.x;
    if (e >= N_EDGES_C) return;
    int s = src[e];
    int d = dst[e];
    int sid = node_ids[s];
    int did = node_ids[d];
    int idx = GENE + 1;                        // cell-cell
    if (sid >= 0 && did < 0) idx = sid;        // gene -> cell
    else if (did >= 0 && sid < 0) idx = did;   // cell -> gene
    else if (sid >= 0 && did >= 0) idx = GENE; // gene -> gene
    float sc = alpha[idx] * ew[e];
    int pos = atomicAdd(&cursor[d], 1);
    csr[pos] = make_int2(s, __float_as_int(sc));
}

// ---------------------------------------------------------------------------
// Fused layer: per block round of 32 nodes:
//   Phase A: each of 4 waves gathers 8 nodes (CSR mean-aggregate, unroll x4,
//            float2 lanes) -> rows[32][100] in LDS
//   Phase B: dense (column-per-thread, W row in VGPRs, 2 groups x 16 rows)
//   Phase C (CLS only): classifier from LDS h2, lin_w staged in LDS
// ---------------------------------------------------------------------------
template <bool CLS>
__global__ __launch_bounds__(256) void fused_layer_kernel(
        const float* __restrict__ hin,
        const int* __restrict__ rp,
        const int2* __restrict__ csr,
        const float* __restrict__ W,      // [100][100]
        const float* __restrict__ b,      // [100]
        const float* __restrict__ lin_w,  // [50][100] (CLS)
        const float* __restrict__ lin_b,  // [50]      (CLS)
        float* __restrict__ outp) {       // [N][100] or [N][50]
    __shared__ float rows[ROWS_PER_BLK][FEATS];
    __shared__ float h2s[CLS ? ROWS_PER_BLK : 1][CLS ? FEATS : 1];
    __shared__ float lws[CLS ? NCLS : 1][CLS ? 108 : 1];

    const int tid = threadIdx.x;
    const int wave = tid >> 6;
    const int lane = tid & 63;
    const int j = tid & 127;      // dense output column
    const int grp = tid >> 7;     // 0,1 : which 16 rows in dense phase
    const int ll = (lane < 49) ? lane : 49;  // float2 lane slot (clamped)

    // W row -> VGPRs (once per block)
    float w[FEATS];
    float bias = 0.0f;
    if (j < FEATS) {
        bias = b[j];
        #pragma unroll
        for (int k4 = 0; k4 < FEATS / 4; ++k4) {
            float4 v = reinterpret_cast<const float4*>(W + (size_t)j * FEATS)[k4];
            w[4 * k4 + 0] = v.x;
            w[4 * k4 + 1] = v.y;
            w[4 * k4 + 2] = v.z;
            w[4 * k4 + 3] = v.w;
        }
    }
    float clinb = 0.0f;
    if (CLS) {
        // stage lin_w into LDS (stride 108 to spread banks), coalesced read
        for (int i = tid; i < NCLS * FEATS; i += 256) {
            int r = i / FEATS;
            lws[r][i - r * FEATS] = lin_w[i];
        }
        if ((tid & 63) < NCLS) clinb = lin_b[tid & 63];
    }
    __syncthreads();   // lws ready (also covers nothing else first round)

    for (int g = blockIdx.x; g < NROUNDS; g += gridDim.x) {
        const int n0 = g * ROWS_PER_BLK;

        // -------- Phase A: gather 8 nodes per wave --------
        for (int i = 0; i < 8; ++i) {
            const int node = n0 + wave * 8 + i;
            const int beg = rp[node];
            const int end = rp[node + 1];
            float ax = 0.0f, ay = 0.0f;
            int k = beg;
            for (; k + 4 <= end; k += 4) {
                int2 e0 = csr[k];
                int2 e1 = csr[k + 1];
                int2 e2 = csr[k + 2];
                int2 e3 = csr[k + 3];
                const float2* r0 = (const float2*)(hin + (size_t)e0.x * FEATS);
                const float2* r1 = (const float2*)(hin + (size_t)e1.x * FEATS);
                const float2* r2 = (const float2*)(hin + (size_t)e2.x * FEATS);
                const float2* r3 = (const float2*)(hin + (size_t)e3.x * FEATS);
                float2 x0 = r0[ll];
                float2 x1 = r1[ll];
                float2 x2 = r2[ll];
                float2 x3 = r3[ll];
                float w0 = __int_as_float(e0.y);
                float w1 = __int_as_float(e1.y);
                float w2 = __int_as_float(e2.y);
                float w3 = __int_as_float(e3.y);
                ax = fmaf(x0.x, w0, ax); ay = fmaf(x0.y, w0, ay);
                ax = fmaf(x1.x, w1, ax); ay = fmaf(x1.y, w1, ay);
                ax = fmaf(x2.x, w2, ax); ay = fmaf(x2.y, w2, ay);
                ax = fmaf(x3.x, w3, ax); ay = fmaf(x3.y, w3, ay);
            }
            for (; k < end; ++k) {
                int2 e = csr[k];
                const float2* r0 = (const float2*)(hin + (size_t)e.x * FEATS);
                float2 x = r0[ll];
                float ww = __int_as_float(e.y);
                ax = fmaf(x.x, ww, ax); ay = fmaf(x.y, ww, ay);
            }
            const float invd = (end > beg) ? 1.0f / (float)(end - beg) : 0.0f;
            if (lane < FEATS / 2) {
                ((float2*)rows[wave * 8 + i])[lane] = make_float2(ax * invd, ay * invd);
            }
        }
        __syncthreads();

        // -------- Phase B: dense (relu(row . W[j] + b[j])) --------
        float acc[16];
        if (j < FEATS) {
            #pragma unroll
            for (int r = 0; r < 16; ++r) acc[r] = bias;
            #pragma unroll
            for (int k4 = 0; k4 < FEATS / 4; ++k4) {
                const float wx = w[4 * k4 + 0];
                const float wy = w[4 * k4 + 1];
                const float wz = w[4 * k4 + 2];
                const float ww = w[4 * k4 + 3];
                #pragma unroll
                for (int r = 0; r < 16; ++r) {
                    float4 hv = *(const float4*)&rows[grp * 16 + r][4 * k4];
                    acc[r] = fmaf(hv.x, wx, acc[r]);
                    acc[r] = fmaf(hv.y, wy, acc[r]);
                    acc[r] = fmaf(hv.z, wz, acc[r]);
                    acc[r] = fmaf(hv.w, ww, acc[r]);
                }
            }
        }

        if (!CLS) {
            if (j < FEATS) {
                #pragma unroll
                for (int r = 0; r < 16; ++r) {
                    outp[(size_t)(n0 + grp * 16 + r) * FEATS + j] = fmaxf(acc[r], 0.0f);
                }
            }
            __syncthreads();   // rows consumed; safe to overwrite next round
        } else {
            if (j < FEATS) {
                #pragma unroll
                for (int r = 0; r < 16; ++r) {
                    h2s[grp * 16 + r][j] = fmaxf(acc[r], 0.0f);
                }
            }
            __syncthreads();   // h2 ready (and rows consumed)

            // -------- Phase C: classifier out = h2 . lin_w[c] + lin_b[c] --------
            const int c = tid & 63;
            const int rg = tid >> 6;    // 0..3 -> rows rg*8..+8
            if (c < NCLS) {
                float cacc[8];
                #pragma unroll
                for (int r = 0; r < 8; ++r) cacc[r] = clinb;
                #pragma unroll
                for (int k4 = 0; k4 < FEATS / 4; ++k4) {
                    float4 lw4 = *(const float4*)&lws[c][4 * k4];
                    #pragma unroll
                    for (int r = 0; r < 8; ++r) {
                        float4 hv = *(const float4*)&h2s[rg * 8 + r][4 * k4];
                        cacc[r] = fmaf(hv.x, lw4.x, cacc[r]);
                        cacc[r] = fmaf(hv.y, lw4.y, cacc[r]);
                        cacc[r] = fmaf(hv.z, lw4.z, cacc[r]);
                        cacc[r] = fmaf(hv.w, lw4.w, cacc[r]);
                    }
                }
                #pragma unroll
                for (int r = 0; r < 8; ++r) {
                    outp[(size_t)(n0 + rg * 8 + r) * NCLS + c] = cacc[r];
                }
            }
            __syncthreads();   // h2/rows consumed; safe to overwrite next round
        }
    }
}

// ---------------------------------------------------------------------------
extern "C" void kernel_launch(void* const* d_in, const int* in_sizes, int n_in,
                              void* d_out, int out_size, void* d_ws, size_t ws_size,
                              hipStream_t stream) {
    const float* features = (const float*)d_in[0];
    const int*   node_ids = (const int*)d_in[1];
    const int*   src      = (const int*)d_in[2];
    const int*   dst      = (const int*)d_in[3];
    const float* ew       = (const float*)d_in[4];
    const float* alpha    = (const float*)d_in[5];
    const float* W1       = (const float*)d_in[6];
    const float* b1       = (const float*)d_in[7];
    const float* W2       = (const float*)d_in[8];
    const float* b2       = (const float*)d_in[9];
    const float* lin_w    = (const float*)d_in[10];
    const float* lin_b    = (const float*)d_in[11];
    float* out = (float*)d_out;

    char* ws = (char*)d_ws;
    size_t off = 0;
    auto alloc = [&](size_t bytes) {
        void* p = ws + off;
        off += (bytes + 255) & ~(size_t)255;
        return p;
    };
    int*  deg    = (int*)alloc((size_t)N_NODES_C * 4);
    int*  bsum   = (int*)alloc((size_t)SCAN_NBLK * 4);
    int*  rp     = (int*)alloc((size_t)(N_NODES_C + 1) * 4);
    int*  cursor = (int*)alloc((size_t)(N_NODES_C + 1) * 4);
    int2* csr    = (int2*)alloc((size_t)N_EDGES_C * 8);
    float* h     = (float*)alloc((size_t)N_NODES_C * FEATS * 4);
    (void)ws_size;

    // --- CSR build ---
    hipMemsetAsync(deg, 0, (size_t)N_NODES_C * 4, stream);
    deg_count_kernel<<<(N_EDGES_C + 255) / 256, 256, 0, stream>>>(dst, deg);
    scan1_kernel<<<SCAN_NBLK, SCAN_BLK, 0, stream>>>(deg, bsum);
    scan2_kernel<<<1, 128, 0, stream>>>(bsum);
    scan3_kernel<<<SCAN_NBLK, SCAN_BLK, 0, stream>>>(deg, bsum, rp, cursor);
    csr_fill_kernel<<<(N_EDGES_C + 255) / 256, 256, 0, stream>>>(
        node_ids, src, dst, ew, alpha, cursor, csr);

    // --- Layer 1 (aggregate + dense fused) ---
    fused_layer_kernel<false><<<768, 256, 0, stream>>>(
        features, rp, csr, W1, b1, nullptr, nullptr, h);

    // --- Layer 2 + classifier (aggregate + dense + linear fused) ---
    fused_layer_kernel<true><<<768, 256, 0, stream>>>(
        h, rp, csr, W2, b2, lin_w, lin_b, out);
}

// Round 4
// 361.457 us; speedup vs baseline: 1.3547x; 1.3547x over previous
//
#include <hip/hip_runtime.h>

#define N_NODES_C 100000
#define N_EDGES_C 800000
#define FEATS 100
#define NCLS 50
#define GENE 20000
#define SCAN_BLK 1024
#define SCAN_NBLK ((N_NODES_C + SCAN_BLK - 1) / SCAN_BLK)   // 98

// ---------------------------------------------------------------------------
// Degree count (int atomics)
// ---------------------------------------------------------------------------
__global__ void deg_count_kernel(const int* __restrict__ dst,
                                 int* __restrict__ deg) {
    int e = blockIdx.x * blockDim.x + threadIdx.x;
    if (e >= N_EDGES_C) return;
    atomicAdd(&deg[dst[e]], 1);
}

// ---------------------------------------------------------------------------
// 3-kernel exclusive scan over deg[100000] -> row_ptr[100001]
// ---------------------------------------------------------------------------
__global__ __launch_bounds__(1024) void scan1_kernel(int* __restrict__ deg,
                                                     int* __restrict__ bsum) {
    __shared__ int wsum[16];
    const int i = blockIdx.x * SCAN_BLK + threadIdx.x;
    const int lane = threadIdx.x & 63;
    const int wid = threadIdx.x >> 6;
    int v = (i < N_NODES_C) ? deg[i] : 0;
    #pragma unroll
    for (int d = 1; d < 64; d <<= 1) {
        int t = __shfl_up(v, d);
        if (lane >= d) v += t;
    }
    if (lane == 63) wsum[wid] = v;
    __syncthreads();
    if (wid == 0) {
        int s = (lane < 16) ? wsum[lane] : 0;
        #pragma unroll
        for (int d = 1; d < 16; d <<= 1) {
            int t = __shfl_up(s, d);
            if (lane >= d) s += t;
        }
        if (lane < 16) wsum[lane] = s;
    }
    __syncthreads();
    if (wid > 0) v += wsum[wid - 1];
    if (i < N_NODES_C) deg[i] = v;
    if (threadIdx.x == SCAN_BLK - 1) bsum[blockIdx.x] = v;
}

__global__ void scan2_kernel(int* __restrict__ bsum) {
    __shared__ int tmp[SCAN_NBLK];
    if (threadIdx.x < SCAN_NBLK) tmp[threadIdx.x] = bsum[threadIdx.x];
    __syncthreads();
    if (threadIdx.x == 0) {
        int off = 0;
        for (int j = 0; j < SCAN_NBLK; ++j) { int t = tmp[j]; tmp[j] = off; off += t; }
    }
    __syncthreads();
    if (threadIdx.x < SCAN_NBLK) bsum[threadIdx.x] = tmp[threadIdx.x];
}

__global__ __launch_bounds__(1024) void scan3_kernel(const int* __restrict__ incl,
                                                     const int* __restrict__ boff,
                                                     int* __restrict__ rp,
                                                     int* __restrict__ cursor) {
    int i = blockIdx.x * SCAN_BLK + threadIdx.x;
    if (i >= N_NODES_C) return;
    int v = incl[i] + boff[blockIdx.x];
    rp[i + 1] = v;
    cursor[i + 1] = v;
    if (i == 0) { rp[0] = 0; cursor[0] = 0; }
}

// ---------------------------------------------------------------------------
// CSR fill: per edge compute scale inline, append (src, scale) to dst bucket
// ---------------------------------------------------------------------------
__global__ void csr_fill_kernel(const int* __restrict__ node_ids,
                                const int* __restrict__ src,
                                const int* __restrict__ dst,
                                const float* __restrict__ ew,
                                const float* __restrict__ alpha,
                                int* __restrict__ cursor,
                                int2* __restrict__ csr) {
    int e = blockIdx.x * blockDim.x + threadIdx.x;
    if (e >= N_EDGES_C) return;
    int s = src[e];
    int d = dst[e];
    int sid = node_ids[s];
    int did = node_ids[d];
    int idx = GENE + 1;                        // cell-cell
    if (sid >= 0 && did < 0) idx = sid;        // gene -> cell
    else if (did >= 0 && sid < 0) idx = did;   // cell -> gene
    else if (sid >= 0 && did >= 0) idx = GENE; // gene -> gene
    float sc = alpha[idx] * ew[e];
    int pos = atomicAdd(&cursor[d], 1);
    csr[pos] = make_int2(s, __float_as_int(sc));
}

// ---------------------------------------------------------------------------
// Aggregation v2: one wave per node, x4 edge unroll (4 independent row loads
// in flight), float2 lanes (50 active), register accumulate, single write.
// ---------------------------------------------------------------------------
__global__ __launch_bounds__(256) void aggregate_kernel(
        const float* __restrict__ hin,
        const int* __restrict__ rp,
        const int2* __restrict__ csr,
        float* __restrict__ neigh) {
    const int node = (blockIdx.x * 256 + threadIdx.x) >> 6;
    const int lane = threadIdx.x & 63;
    const int ll = (lane < FEATS / 2) ? lane : (FEATS / 2 - 1);  // clamp, safe reads
    if (node >= N_NODES_C) return;
    const int beg = rp[node];
    const int end = rp[node + 1];
    float ax = 0.0f, ay = 0.0f;
    int k = beg;
    for (; k + 4 <= end; k += 4) {
        int2 e0 = csr[k];
        int2 e1 = csr[k + 1];
        int2 e2 = csr[k + 2];
        int2 e3 = csr[k + 3];
        const float2* r0 = (const float2*)(hin + (size_t)e0.x * FEATS);
        const float2* r1 = (const float2*)(hin + (size_t)e1.x * FEATS);
        const float2* r2 = (const float2*)(hin + (size_t)e2.x * FEATS);
        const float2* r3 = (const float2*)(hin + (size_t)e3.x * FEATS);
        float2 x0 = r0[ll];
        float2 x1 = r1[ll];
        float2 x2 = r2[ll];
        float2 x3 = r3[ll];
        float w0 = __int_as_float(e0.y);
        float w1 = __int_as_float(e1.y);
        float w2 = __int_as_float(e2.y);
        float w3 = __int_as_float(e3.y);
        ax = fmaf(x0.x, w0, ax); ay = fmaf(x0.y, w0, ay);
        ax = fmaf(x1.x, w1, ax); ay = fmaf(x1.y, w1, ay);
        ax = fmaf(x2.x, w2, ax); ay = fmaf(x2.y, w2, ay);
        ax = fmaf(x3.x, w3, ax); ay = fmaf(x3.y, w3, ay);
    }
    for (; k < end; ++k) {
        int2 e = csr[k];
        const float2* r0 = (const float2*)(hin + (size_t)e.x * FEATS);
        float2 x = r0[ll];
        float ww = __int_as_float(e.y);
        ax = fmaf(x.x, ww, ax); ay = fmaf(x.y, ww, ay);
    }
    const float invd = (end > beg) ? 1.0f / (float)(end - beg) : 0.0f;
    if (lane < FEATS / 2) {
        ((float2*)(neigh + (size_t)node * FEATS))[lane] =
            make_float2(ax * invd, ay * invd);
    }
}

// ---------------------------------------------------------------------------
// Dense: one 32-row round per block (grid = N/32 = 3125). 256 threads.
// NOUT=100: 2 groups x 16 rows, j = tid&127 (<100 active)
// NOUT=50 : 4 groups x  8 rows, j = tid&63  (<50 active)
// W row in VGPRs; rows staged float4; broadcast LDS reads.
// ---------------------------------------------------------------------------
template <int NOUT, bool RELU>
__global__ __launch_bounds__(256) void dense32_kernel(
        const float* __restrict__ in,
        const float* __restrict__ W,
        const float* __restrict__ b,
        float* __restrict__ out) {
    constexpr int RPT   = (NOUT == 100) ? 16 : 8;   // rows per thread
    constexpr int JMASK = (NOUT == 100) ? 127 : 63;
    constexpr int GS    = (NOUT == 100) ? 7 : 6;

    __shared__ float rows[32][FEATS];
    const int tid = threadIdx.x;
    const int n0 = blockIdx.x * 32;
    const int j = tid & JMASK;
    const int grp = tid >> GS;

    // Stage 32 input rows as float4 (800 items over 256 threads)
    for (int i = tid; i < 32 * (FEATS / 4); i += 256) {
        int r = i / (FEATS / 4);
        int k4 = i - r * (FEATS / 4);
        float4 v = reinterpret_cast<const float4*>(in + (size_t)(n0 + r) * FEATS)[k4];
        *reinterpret_cast<float4*>(&rows[r][k4 * 4]) = v;
    }

    // W row -> VGPRs
    float w[FEATS];
    float bias = 0.0f;
    if (j < NOUT) {
        bias = b[j];
        #pragma unroll
        for (int k4 = 0; k4 < FEATS / 4; ++k4) {
            float4 v = reinterpret_cast<const float4*>(W + (size_t)j * FEATS)[k4];
            w[4 * k4 + 0] = v.x;
            w[4 * k4 + 1] = v.y;
            w[4 * k4 + 2] = v.z;
            w[4 * k4 + 3] = v.w;
        }
    }
    __syncthreads();

    if (j < NOUT) {
        float acc[RPT];
        #pragma unroll
        for (int r = 0; r < RPT; ++r) acc[r] = bias;
        #pragma unroll
        for (int k4 = 0; k4 < FEATS / 4; ++k4) {
            const float wx = w[4 * k4 + 0];
            const float wy = w[4 * k4 + 1];
            const float wz = w[4 * k4 + 2];
            const float ww = w[4 * k4 + 3];
            #pragma unroll
            for (int r = 0; r < RPT; ++r) {
                float4 hv = *reinterpret_cast<const float4*>(&rows[grp * RPT + r][4 * k4]);
                acc[r] = fmaf(hv.x, wx, acc[r]);
                acc[r] = fmaf(hv.y, wy, acc[r]);
                acc[r] = fmaf(hv.z, wz, acc[r]);
                acc[r] = fmaf(hv.w, ww, acc[r]);
            }
        }
        #pragma unroll
        for (int r = 0; r < RPT; ++r) {
            float v = RELU ? fmaxf(acc[r], 0.0f) : acc[r];
            out[(size_t)(n0 + grp * RPT + r) * NOUT + j] = v;
        }
    }
}

// ---------------------------------------------------------------------------
extern "C" void kernel_launch(void* const* d_in, const int* in_sizes, int n_in,
                              void* d_out, int out_size, void* d_ws, size_t ws_size,
                              hipStream_t stream) {
    const float* features = (const float*)d_in[0];
    const int*   node_ids = (const int*)d_in[1];
    const int*   src      = (const int*)d_in[2];
    const int*   dst      = (const int*)d_in[3];
    const float* ew       = (const float*)d_in[4];
    const float* alpha    = (const float*)d_in[5];
    const float* W1       = (const float*)d_in[6];
    const float* b1       = (const float*)d_in[7];
    const float* W2       = (const float*)d_in[8];
    const float* b2       = (const float*)d_in[9];
    const float* lin_w    = (const float*)d_in[10];
    const float* lin_b    = (const float*)d_in[11];
    float* out = (float*)d_out;

    char* ws = (char*)d_ws;
    size_t off = 0;
    auto alloc = [&](size_t bytes) {
        void* p = ws + off;
        off += (bytes + 255) & ~(size_t)255;
        return p;
    };
    int*  deg    = (int*)alloc((size_t)N_NODES_C * 4);
    int*  bsum   = (int*)alloc((size_t)SCAN_NBLK * 4);
    int*  rp     = (int*)alloc((size_t)(N_NODES_C + 1) * 4);
    int*  cursor = (int*)alloc((size_t)(N_NODES_C + 1) * 4);
    int2* csr    = (int2*)alloc((size_t)N_EDGES_C * 8);
    float* neigh = (float*)alloc((size_t)N_NODES_C * FEATS * 4);
    float* h     = (float*)alloc((size_t)N_NODES_C * FEATS * 4);
    (void)ws_size;

    // --- CSR build ---
    hipMemsetAsync(deg, 0, (size_t)N_NODES_C * 4, stream);
    deg_count_kernel<<<(N_EDGES_C + 255) / 256, 256, 0, stream>>>(dst, deg);
    scan1_kernel<<<SCAN_NBLK, SCAN_BLK, 0, stream>>>(deg, bsum);
    scan2_kernel<<<1, 128, 0, stream>>>(bsum);
    scan3_kernel<<<SCAN_NBLK, SCAN_BLK, 0, stream>>>(deg, bsum, rp, cursor);
    csr_fill_kernel<<<(N_EDGES_C + 255) / 256, 256, 0, stream>>>(
        node_ids, src, dst, ew, alpha, cursor, csr);

    // --- Layer 1 ---
    aggregate_kernel<<<(N_NODES_C * 64) / 256, 256, 0, stream>>>(features, rp, csr, neigh);
    dense32_kernel<FEATS, true><<<N_NODES_C / 32, 256, 0, stream>>>(neigh, W1, b1, h);

    // --- Layer 2 ---
    aggregate_kernel<<<(N_NODES_C * 64) / 256, 256, 0, stream>>>(h, rp, csr, neigh);
    dense32_kernel<FEATS, true><<<N_NODES_C / 32, 256, 0, stream>>>(neigh, W2, b2, h);

    // --- Classifier ---
    dense32_kernel<NCLS, false><<<N_NODES_C / 32, 256, 0, stream>>>(h, lin_w, lin_b, out);
}